// Round 7
// baseline (584.073 us; speedup 1.0000x reference)
//
#include <hip/hip_runtime.h>
#include <hip/hip_cooperative_groups.h>
#include <stdint.h>

// AttentionReadout: G=1024 x N=64, D=512, H=8, hd=64. fp32 I/O, bf16 MFMA.
// v12: ONE cooperative persistent kernel (256 blocks = 1/CU, guaranteed
// co-resident at 144.9KB LDS). Phases: convert+upart -> grid.sync ->
// attn loop (4 graphs/block, v10 body verbatim + trailing barrier) ->
// grid.sync -> outproj (1 job/block, 8 waves). Fallback to proven v10
// 3-kernel path if cooperative launch fails.
// v11 post-mortem: LDS 145->69KB left occupancy at 23% => limiter is the
// unified reg file (~108 arch + ~70 acc ~= 180 total -> 2 waves/SIMD,
// structural for the 64x64-per-wave blocking). scr back in LDS (global
// scr cost +18us HBM round-trip). Occupancy lever closed; this round
// banks launch/gap overhead (~11us per kernel, v0->v10 measurement).

namespace cg = cooperative_groups;

typedef __attribute__((ext_vector_type(8))) short short8;   // 8 bf16
typedef __attribute__((ext_vector_type(4))) float f32x4;    // MFMA C/D frag

#define D_ 512

// ---- ws layout (bytes) ----
#define WQKV_OFF   0u          // 1536*512 bf16 = 1572864
#define WO_OFF     1572864u    // 512*512 bf16  = 524288
#define UPART_OFF  2097152u    // 16*512 f32    = 32768
#define SG_OFF     2132032u    // 1024 f32      = 4096
#define WCTX_OFF   2136128u    // 1024*512 bf16 = 1 MB

__device__ __forceinline__ unsigned short f2bf(float f) {
    union { float f; unsigned int u; } t; t.f = f;
    unsigned int u = t.u;
    return (unsigned short)((u + 0x7FFFu + ((u >> 16) & 1u)) >> 16);  // RNE
}
__device__ __forceinline__ unsigned pack2(float a, float b) {
    return (unsigned)f2bf(a) | ((unsigned)f2bf(b) << 16);
}

union U8 { unsigned u[4]; short8 s; };

// ======================================================================
// v12: single cooperative kernel. 256 blocks x 512 thr, LDS ~145KB.
// ======================================================================
__global__ __launch_bounds__(512, 2)
void fused_all(const float* __restrict__ x,            // [65536,512] f32
               const float* __restrict__ wqkv_f,       // [1536,512] f32
               const float* __restrict__ wo_f,         // [512,512] f32
               const float* __restrict__ bqkv,         // [1536] f32
               const float* __restrict__ bo,           // [512] f32
               const float* __restrict__ gw,           // [512] f32
               const float* __restrict__ gb,           // [1] f32
               unsigned short* __restrict__ wbf,       // ws: wqkv_bf||wo_bf
               float* __restrict__ upart,              // ws: [16,512]
               unsigned short* __restrict__ wctx_ws,   // ws: [G,512] bf16
               float* __restrict__ sumgate,            // ws: [G] f32
               float* __restrict__ out,                // [G,512] f32
               int G)
{
    __shared__ unsigned short xs[64][520];     // 66560 B
    __shared__ unsigned short scr[8][64][72];  // 73728 B (vT then P, per wave)
    __shared__ float logitp[8][64];            // 2048 B
    __shared__ float gatev[64];                // 256 B
    __shared__ float u_s[512];                 // 2048 B
    __shared__ float c0_s;
    // ~144.7 KB -> 1 block/CU; 256 blocks co-resident (cooperative-safe)

    const int bid  = blockIdx.x;
    const int tid  = threadIdx.x;
    const int w    = tid >> 6;      // wave = head
    const int lane = tid & 63;
    const int l15  = lane & 15;
    const int quad = lane >> 4;

    // ======== phase 1: weights fp32 -> bf16; upart (blocks 0..15) ========
    for (int i4 = bid * 512 + tid; i4 < 262144; i4 += 256 * 512) {
        float4 v;
        if (i4 < 196608) v = *(const float4*)(wqkv_f + (size_t)i4 * 4);
        else             v = *(const float4*)(wo_f   + (size_t)(i4 - 196608) * 4);
        uint2 p; p.x = pack2(v.x, v.y); p.y = pack2(v.z, v.w);
        *(uint2*)(wbf + (size_t)i4 * 4) = p;
    }
    if (bid < 16) {   // upart[bid][d] = sum_{e in bid*32..+32} wo[e][d]*gw[e]
        float a = 0.f;
        #pragma unroll 4
        for (int e = bid * 32; e < bid * 32 + 32; ++e)
            a += wo_f[(size_t)e * 512 + tid] * gw[e];
        upart[bid * 512 + tid] = a;
    }
    cg::this_grid().sync();

    const unsigned short* wqkv  = wbf;           // [1536,512] bf16
    const unsigned short* wo_bf = wbf + 786432;  // [512,512] bf16

    // ---- u_s / c0 once per block (persistent across the graph loop) ----
    {
        float s = 0.f;
        #pragma unroll
        for (int b = 0; b < 16; ++b) s += upart[b*512 + tid];
        u_s[tid] = s;
    }
    if (tid < 64) {
        float s = 0.f;
        #pragma unroll
        for (int i = 0; i < 8; ++i) s += bo[tid*8 + i] * gw[tid*8 + i];
        s += __shfl_xor(s, 1);  s += __shfl_xor(s, 2);  s += __shfl_xor(s, 4);
        s += __shfl_xor(s, 8);  s += __shfl_xor(s, 16); s += __shfl_xor(s, 32);
        if (tid == 0) c0_s = s + gb[0];
    }
    __syncthreads();

    const int h = w;
    unsigned short (*S)[72] = scr[w];

    // ======== phase 2: attn, 4 graphs per block (v10 body verbatim) ========
    for (int g = bid; g < G; g += 256) {
        // ---- stage x: fp32 -> bf16 LDS ----
        #pragma unroll
        for (int i = 0; i < 16; ++i) {
            int idx = tid + i * 512;
            int row = idx >> 7;
            int c4  = idx & 127;
            float4 v = *(const float4*)(x + ((size_t)(g*64 + row))*512 + c4*4);
            uint2 p; p.x = pack2(v.x, v.y); p.y = pack2(v.z, v.w);
            *(uint2*)(&xs[row][c4*4]) = p;
        }
        __syncthreads();   // (1)

        // ---- QKV for head h (K=512), score frags built in-register ----
        U8 qA[4][2], kB[4][2];
        #pragma unroll
        for (int dt = 0; dt < 4; ++dt) {
            f32x4 aq[4], ak[4], av[4];
            #pragma unroll
            for (int nt = 0; nt < 4; ++nt) {
                aq[nt] = (f32x4){0.f,0.f,0.f,0.f};
                ak[nt] = (f32x4){0.f,0.f,0.f,0.f};
                av[nt] = (f32x4){0.f,0.f,0.f,0.f};
            }
            const unsigned short* wq = wqkv + (size_t)(          h*64 + dt*16 + l15) * 512;
            const unsigned short* wk = wqkv + (size_t)( 512 +    h*64 + dt*16 + l15) * 512;
            const unsigned short* wv = wqkv + (size_t)(1024 +    h*64 + dt*16 + l15) * 512;
            #pragma unroll 4
            for (int ks = 0; ks < 16; ++ks) {
                const int col = ks*32 + quad*8;
                short8 a0 = *(const short8*)(wq + col);
                short8 a1 = *(const short8*)(wk + col);
                short8 a2 = *(const short8*)(wv + col);
                #pragma unroll
                for (int nt = 0; nt < 4; ++nt) {
                    short8 b = *(const short8*)(&xs[nt*16 + l15][col]);
                    aq[nt] = __builtin_amdgcn_mfma_f32_16x16x32_bf16(a0, b, aq[nt], 0,0,0);
                    ak[nt] = __builtin_amdgcn_mfma_f32_16x16x32_bf16(a1, b, ak[nt], 0,0,0);
                    av[nt] = __builtin_amdgcn_mfma_f32_16x16x32_bf16(a2, b, av[nt], 0,0,0);
                }
            }
            float bq[4], bk2[4], bv2[4];
            #pragma unroll
            for (int r = 0; r < 4; ++r) {
                bq[r]  = bqkv[          h*64 + dt*16 + quad*4 + r];
                bk2[r] = bqkv[ 512 +    h*64 + dt*16 + quad*4 + r];
                bv2[r] = bqkv[1024 +    h*64 + dt*16 + quad*4 + r];
            }
            const bool take = ((quad >> 1) == (dt & 1));
            const int  ks2  = dt >> 1;
            #pragma unroll
            for (int nt = 0; nt < 4; ++nt) {
                unsigned q01 = pack2(aq[nt][0]+bq[0],  aq[nt][1]+bq[1]);
                unsigned q23 = pack2(aq[nt][2]+bq[2],  aq[nt][3]+bq[3]);
                unsigned k01 = pack2(ak[nt][0]+bk2[0], ak[nt][1]+bk2[1]);
                unsigned k23 = pack2(ak[nt][2]+bk2[2], ak[nt][3]+bk2[3]);
                #pragma unroll
                for (int j = 0; j < 4; ++j) {
                    int srcl = ((quad & 1)*2 + (j >> 1))*16 + l15;
                    unsigned tq = (unsigned)__shfl((int)((j & 1) ? q23 : q01), srcl);
                    unsigned tk = (unsigned)__shfl((int)((j & 1) ? k23 : k01), srcl);
                    if (take) { qA[nt][ks2].u[j] = tq; kB[nt][ks2].u[j] = tk; }
                }
                #pragma unroll
                for (int r = 0; r < 4; ++r)
                    S[dt*16 + quad*4 + r][nt*16 + l15] = f2bf(av[nt][r] + bv2[r]);
            }
        }

        // ---- scores (64x64 per wave) ----
        f32x4 sacc[4][4];
        #pragma unroll
        for (int a = 0; a < 4; ++a)
            #pragma unroll
            for (int b = 0; b < 4; ++b) sacc[a][b] = (f32x4){0.f,0.f,0.f,0.f};
        #pragma unroll
        for (int ks2 = 0; ks2 < 2; ++ks2)
            #pragma unroll
            for (int a = 0; a < 4; ++a)
                #pragma unroll
                for (int b = 0; b < 4; ++b)
                    sacc[a][b] = __builtin_amdgcn_mfma_f32_16x16x32_bf16(
                                     qA[a][ks2].s, kB[b][ks2].s, sacc[a][b], 0,0,0);

        // ---- softmax over m ----
        #pragma unroll
        for (int a = 0; a < 4; ++a) {
            #pragma unroll
            for (int r = 0; r < 4; ++r) {
                float m0 = -1e30f;
                #pragma unroll
                for (int b = 0; b < 4; ++b) { sacc[a][b][r] *= 0.125f; m0 = fmaxf(m0, sacc[a][b][r]); }
                m0 = fmaxf(m0, __shfl_xor(m0, 1));
                m0 = fmaxf(m0, __shfl_xor(m0, 2));
                m0 = fmaxf(m0, __shfl_xor(m0, 4));
                m0 = fmaxf(m0, __shfl_xor(m0, 8));
                float s = 0.f;
                #pragma unroll
                for (int b = 0; b < 4; ++b) { float e = __expf(sacc[a][b][r] - m0); sacc[a][b][r] = e; s += e; }
                s += __shfl_xor(s, 1); s += __shfl_xor(s, 2); s += __shfl_xor(s, 4); s += __shfl_xor(s, 8);
                float inv = 1.0f / s;
                #pragma unroll
                for (int b = 0; b < 4; ++b) sacc[a][b][r] *= inv;
            }
        }

        // ---- vA extract, P write, pB read (in-order DS, wave-local) ----
        U8 vA[4][2];
        #pragma unroll
        for (int dtile = 0; dtile < 4; ++dtile)
            #pragma unroll
            for (int ks2 = 0; ks2 < 2; ++ks2)
                vA[dtile][ks2].s = *(const short8*)(&S[dtile*16 + l15][ks2*32 + quad*8]);

        #pragma unroll
        for (int a = 0; a < 4; ++a)
            #pragma unroll
            for (int b = 0; b < 4; ++b)
                #pragma unroll
                for (int r = 0; r < 4; ++r)
                    S[a*16 + quad*4 + r][b*16 + l15] = f2bf(sacc[a][b][r]);

        U8 pB[4][2];
        #pragma unroll
        for (int a = 0; a < 4; ++a)
            #pragma unroll
            for (int ks2 = 0; ks2 < 2; ++ks2)
                pB[a][ks2].s = *(const short8*)(&S[a*16 + l15][ks2*32 + quad*8]);

        // ---- PV ----
        f32x4 cacc[4][4];
        #pragma unroll
        for (int dtile = 0; dtile < 4; ++dtile)
            #pragma unroll
            for (int a = 0; a < 4; ++a) cacc[dtile][a] = (f32x4){0.f,0.f,0.f,0.f};
        #pragma unroll
        for (int ks2 = 0; ks2 < 2; ++ks2)
            #pragma unroll
            for (int dtile = 0; dtile < 4; ++dtile)
                #pragma unroll
                for (int a = 0; a < 4; ++a)
                    cacc[dtile][a] = __builtin_amdgcn_mfma_f32_16x16x32_bf16(
                                         vA[dtile][ks2].s, pB[a][ks2].s, cacc[dtile][a], 0,0,0);

        // ---- gate-logit partials ----
        {
            float uv[4][4];
            #pragma unroll
            for (int dtile = 0; dtile < 4; ++dtile)
                #pragma unroll
                for (int r = 0; r < 4; ++r)
                    uv[dtile][r] = u_s[h*64 + dtile*16 + quad*4 + r];
            #pragma unroll
            for (int a = 0; a < 4; ++a) {
                float s = 0.f;
                #pragma unroll
                for (int dtile = 0; dtile < 4; ++dtile)
                    #pragma unroll
                    for (int r = 0; r < 4; ++r)
                        s += cacc[dtile][a][r] * uv[dtile][r];
                s += __shfl_xor(s, 16); s += __shfl_xor(s, 32);
                if (quad == 0) logitp[w][a*16 + l15] = s;
            }
        }
        __syncthreads();   // (2)

        if (tid < 64) {
            float lg = c0_s;
            #pragma unroll
            for (int ww = 0; ww < 8; ++ww) lg += logitp[ww][tid];
            float gt = 1.0f / (1.0f + __expf(-lg));
            gatev[tid] = gt;
            float s = gt;
            s += __shfl_xor(s, 1);  s += __shfl_xor(s, 2);  s += __shfl_xor(s, 4);
            s += __shfl_xor(s, 8);  s += __shfl_xor(s, 16); s += __shfl_xor(s, 32);
            if (tid == 0) sumgate[g] = s;
        }
        __syncthreads();   // (3)

        // ---- wctx ----
        {
            float gv[4];
            #pragma unroll
            for (int a = 0; a < 4; ++a) gv[a] = gatev[a*16 + l15];
            #pragma unroll
            for (int dtile = 0; dtile < 4; ++dtile) {
                float sr[4];
                #pragma unroll
                for (int r = 0; r < 4; ++r) {
                    float s = cacc[dtile][0][r]*gv[0] + cacc[dtile][1][r]*gv[1]
                            + cacc[dtile][2][r]*gv[2] + cacc[dtile][3][r]*gv[3];
                    s += __shfl_xor(s, 1); s += __shfl_xor(s, 2);
                    s += __shfl_xor(s, 4); s += __shfl_xor(s, 8);
                    sr[r] = s;
                }
                if (l15 == 0) {
                    uint2 pk; pk.x = pack2(sr[0], sr[1]); pk.y = pack2(sr[2], sr[3]);
                    *(uint2*)(wctx_ws + (size_t)g*512 + h*64 + dtile*16 + quad*4) = pk;
                }
            }
        }
        __syncthreads();   // (4) trailing: keep all waves' barriers aligned
                           //     across iterations (xs reuse + barrier pairing)
    }

    cg::this_grid().sync();

    // ======== phase 3: outproj, 1 job/block (8 waves x 16 e each) ========
    const int GX = G >> 4;                      // g-blocks of 16
    for (int job = bid; job < GX * 4; job += 256) {
        const int gx = job % GX;
        const int e0 = (job / GX) * 128;
        const int g0 = gx * 16;
        f32x4 oac = (f32x4){0.f,0.f,0.f,0.f};
        #pragma unroll 4
        for (int ks = 0; ks < 16; ++ks) {
            const int col = ks*32 + quad*8;
            short8 a = *(const short8*)(wctx_ws + (size_t)(g0 + l15)*D_ + col);
            short8 b = *(const short8*)(wo_bf + (size_t)(e0 + w*16 + l15)*D_ + col);
            oac = __builtin_amdgcn_mfma_f32_16x16x32_bf16(a, b, oac, 0,0,0);
        }
        const int e = e0 + w*16 + l15;
        const float bov = bo[e];
        #pragma unroll
        for (int r = 0; r < 4; ++r) {
            const int gg = g0 + quad*4 + r;
            out[(size_t)gg*D_ + e] = oac[r] + sumgate[gg] * bov;
        }
    }
}

// ======================================================================
// FALLBACK path: v10's proven 3 kernels (423.5us), verbatim
// ======================================================================
__global__ __launch_bounds__(256)
void convert_weights(const float* __restrict__ wqkv, const float* __restrict__ wo,
                     unsigned short* __restrict__ wbf,
                     const float* __restrict__ gw, float* __restrict__ upart) {
    if (blockIdx.x >= 1024) {
        const int b = blockIdx.x - 1024;
        const int t = threadIdx.x;
        float a0 = 0.f, a1 = 0.f;
        #pragma unroll 4
        for (int e = b * 32; e < b * 32 + 32; ++e) {
            const float ge = gw[e];
            a0 += wo[(size_t)e * 512 + t]       * ge;
            a1 += wo[(size_t)e * 512 + t + 256] * ge;
        }
        upart[b * 512 + t] = a0; upart[b * 512 + t + 256] = a1;
        return;
    }
    const int i4 = blockIdx.x * 256 + threadIdx.x;
    float4 v;
    if (i4 < 196608) v = *(const float4*)(wqkv + (size_t)i4 * 4);
    else             v = *(const float4*)(wo   + (size_t)(i4 - 196608) * 4);
    uint2 p; p.x = pack2(v.x, v.y); p.y = pack2(v.z, v.w);
    *(uint2*)(wbf + (size_t)i4 * 4) = p;
}

__global__ __launch_bounds__(512, 2)
void attn_ctx_kernel(const float* __restrict__ x,
                     const unsigned short* __restrict__ wqkv,
                     const float* __restrict__ bqkv,
                     const float* __restrict__ upart,
                     const float* __restrict__ bo,
                     const float* __restrict__ gw,
                     const float* __restrict__ gb,
                     unsigned short* __restrict__ wctx_ws,
                     float* __restrict__ sumgate)
{
    __shared__ unsigned short xs[64][520];
    __shared__ unsigned short scr[8][64][72];
    __shared__ float logitp[8][64];
    __shared__ float gatev[64];
    __shared__ float u_s[512];
    __shared__ float c0_s;

    const int g    = blockIdx.x;
    const int tid  = threadIdx.x;
    const int w    = tid >> 6;
    const int lane = tid & 63;
    const int l15  = lane & 15;
    const int quad = lane >> 4;

    #pragma unroll
    for (int i = 0; i < 16; ++i) {
        int idx = tid + i * 512;
        int row = idx >> 7;
        int c4  = idx & 127;
        float4 v = *(const float4*)(x + ((size_t)(g*64 + row))*512 + c4*4);
        uint2 p; p.x = pack2(v.x, v.y); p.y = pack2(v.z, v.w);
        *(uint2*)(&xs[row][c4*4]) = p;
    }
    {
        float s = 0.f;
        #pragma unroll
        for (int b = 0; b < 16; ++b) s += upart[b*512 + tid];
        u_s[tid] = s;
    }
    if (tid < 64) {
        float s = 0.f;
        #pragma unroll
        for (int i = 0; i < 8; ++i) s += bo[tid*8 + i] * gw[tid*8 + i];
        s += __shfl_xor(s, 1);  s += __shfl_xor(s, 2);  s += __shfl_xor(s, 4);
        s += __shfl_xor(s, 8);  s += __shfl_xor(s, 16); s += __shfl_xor(s, 32);
        if (tid == 0) c0_s = s + gb[0];
    }
    __syncthreads();

    const int h = w;
    unsigned short (*S)[72] = scr[w];

    U8 qA[4][2], kB[4][2];
    #pragma unroll
    for (int dt = 0; dt < 4; ++dt) {
        f32x4 aq[4], ak[4], av[4];
        #pragma unroll
        for (int nt = 0; nt < 4; ++nt) {
            aq[nt] = (f32x4){0.f,0.f,0.f,0.f};
            ak[nt] = (f32x4){0.f,0.f,0.f,0.f};
            av[nt] = (f32x4){0.f,0.f,0.f,0.f};
        }
        const unsigned short* wq = wqkv + (size_t)(          h*64 + dt*16 + l15) * 512;
        const unsigned short* wk = wqkv + (size_t)( 512 +    h*64 + dt*16 + l15) * 512;
        const unsigned short* wv = wqkv + (size_t)(1024 +    h*64 + dt*16 + l15) * 512;
        #pragma unroll 4
        for (int ks = 0; ks < 16; ++ks) {
            const int col = ks*32 + quad*8;
            short8 a0 = *(const short8*)(wq + col);
            short8 a1 = *(const short8*)(wk + col);
            short8 a2 = *(const short8*)(wv + col);
            #pragma unroll
            for (int nt = 0; nt < 4; ++nt) {
                short8 b = *(const short8*)(&xs[nt*16 + l15][col]);
                aq[nt] = __builtin_amdgcn_mfma_f32_16x16x32_bf16(a0, b, aq[nt], 0,0,0);
                ak[nt] = __builtin_amdgcn_mfma_f32_16x16x32_bf16(a1, b, ak[nt], 0,0,0);
                av[nt] = __builtin_amdgcn_mfma_f32_16x16x32_bf16(a2, b, av[nt], 0,0,0);
            }
        }
        float bq[4], bk2[4], bv2[4];
        #pragma unroll
        for (int r = 0; r < 4; ++r) {
            bq[r]  = bqkv[          h*64 + dt*16 + quad*4 + r];
            bk2[r] = bqkv[ 512 +    h*64 + dt*16 + quad*4 + r];
            bv2[r] = bqkv[1024 +    h*64 + dt*16 + quad*4 + r];
        }
        const bool take = ((quad >> 1) == (dt & 1));
        const int  ks2  = dt >> 1;
        #pragma unroll
        for (int nt = 0; nt < 4; ++nt) {
            unsigned q01 = pack2(aq[nt][0]+bq[0],  aq[nt][1]+bq[1]);
            unsigned q23 = pack2(aq[nt][2]+bq[2],  aq[nt][3]+bq[3]);
            unsigned k01 = pack2(ak[nt][0]+bk2[0], ak[nt][1]+bk2[1]);
            unsigned k23 = pack2(ak[nt][2]+bk2[2], ak[nt][3]+bk2[3]);
            #pragma unroll
            for (int j = 0; j < 4; ++j) {
                int srcl = ((quad & 1)*2 + (j >> 1))*16 + l15;
                unsigned tq = (unsigned)__shfl((int)((j & 1) ? q23 : q01), srcl);
                unsigned tk = (unsigned)__shfl((int)((j & 1) ? k23 : k01), srcl);
                if (take) { qA[nt][ks2].u[j] = tq; kB[nt][ks2].u[j] = tk; }
            }
            #pragma unroll
            for (int r = 0; r < 4; ++r)
                S[dt*16 + quad*4 + r][nt*16 + l15] = f2bf(av[nt][r] + bv2[r]);
        }
    }

    f32x4 sacc[4][4];
    #pragma unroll
    for (int a = 0; a < 4; ++a)
        #pragma unroll
        for (int b = 0; b < 4; ++b) sacc[a][b] = (f32x4){0.f,0.f,0.f,0.f};
    #pragma unroll
    for (int ks2 = 0; ks2 < 2; ++ks2)
        #pragma unroll
        for (int a = 0; a < 4; ++a)
            #pragma unroll
            for (int b = 0; b < 4; ++b)
                sacc[a][b] = __builtin_amdgcn_mfma_f32_16x16x32_bf16(
                                 qA[a][ks2].s, kB[b][ks2].s, sacc[a][b], 0,0,0);

    #pragma unroll
    for (int a = 0; a < 4; ++a) {
        #pragma unroll
        for (int r = 0; r < 4; ++r) {
            float m0 = -1e30f;
            #pragma unroll
            for (int b = 0; b < 4; ++b) { sacc[a][b][r] *= 0.125f; m0 = fmaxf(m0, sacc[a][b][r]); }
            m0 = fmaxf(m0, __shfl_xor(m0, 1));
            m0 = fmaxf(m0, __shfl_xor(m0, 2));
            m0 = fmaxf(m0, __shfl_xor(m0, 4));
            m0 = fmaxf(m0, __shfl_xor(m0, 8));
            float s = 0.f;
            #pragma unroll
            for (int b = 0; b < 4; ++b) { float e = __expf(sacc[a][b][r] - m0); sacc[a][b][r] = e; s += e; }
            s += __shfl_xor(s, 1); s += __shfl_xor(s, 2); s += __shfl_xor(s, 4); s += __shfl_xor(s, 8);
            float inv = 1.0f / s;
            #pragma unroll
            for (int b = 0; b < 4; ++b) sacc[a][b][r] *= inv;
        }
    }

    U8 vA[4][2];
    #pragma unroll
    for (int dtile = 0; dtile < 4; ++dtile)
        #pragma unroll
        for (int ks2 = 0; ks2 < 2; ++ks2)
            vA[dtile][ks2].s = *(const short8*)(&S[dtile*16 + l15][ks2*32 + quad*8]);

    #pragma unroll
    for (int a = 0; a < 4; ++a)
        #pragma unroll
        for (int b = 0; b < 4; ++b)
            #pragma unroll
            for (int r = 0; r < 4; ++r)
                S[a*16 + quad*4 + r][b*16 + l15] = f2bf(sacc[a][b][r]);

    U8 pB[4][2];
    #pragma unroll
    for (int a = 0; a < 4; ++a)
        #pragma unroll
        for (int ks2 = 0; ks2 < 2; ++ks2)
            pB[a][ks2].s = *(const short8*)(&S[a*16 + l15][ks2*32 + quad*8]);

    f32x4 cacc[4][4];
    #pragma unroll
    for (int dtile = 0; dtile < 4; ++dtile)
        #pragma unroll
        for (int a = 0; a < 4; ++a) cacc[dtile][a] = (f32x4){0.f,0.f,0.f,0.f};
    #pragma unroll
    for (int ks2 = 0; ks2 < 2; ++ks2)
        #pragma unroll
        for (int dtile = 0; dtile < 4; ++dtile)
            #pragma unroll
            for (int a = 0; a < 4; ++a)
                cacc[dtile][a] = __builtin_amdgcn_mfma_f32_16x16x32_bf16(
                                     vA[dtile][ks2].s, pB[a][ks2].s, cacc[dtile][a], 0,0,0);

    {
        float uv[4][4];
        #pragma unroll
        for (int dtile = 0; dtile < 4; ++dtile)
            #pragma unroll
            for (int r = 0; r < 4; ++r)
                uv[dtile][r] = u_s[h*64 + dtile*16 + quad*4 + r];
        #pragma unroll
        for (int a = 0; a < 4; ++a) {
            float s = 0.f;
            #pragma unroll
            for (int dtile = 0; dtile < 4; ++dtile)
                #pragma unroll
                for (int r = 0; r < 4; ++r)
                    s += cacc[dtile][a][r] * uv[dtile][r];
            s += __shfl_xor(s, 16); s += __shfl_xor(s, 32);
            if (quad == 0) logitp[w][a*16 + l15] = s;
        }
    }
    __syncthreads();

    if (tid < 64) {
        float lg = c0_s;
        #pragma unroll
        for (int ww = 0; ww < 8; ++ww) lg += logitp[ww][tid];
        float gt = 1.0f / (1.0f + __expf(-lg));
        gatev[tid] = gt;
        float s = gt;
        s += __shfl_xor(s, 1);  s += __shfl_xor(s, 2);  s += __shfl_xor(s, 4);
        s += __shfl_xor(s, 8);  s += __shfl_xor(s, 16); s += __shfl_xor(s, 32);
        if (tid == 0) sumgate[g] = s;
    }
    __syncthreads();

    {
        float gv[4];
        #pragma unroll
        for (int a = 0; a < 4; ++a) gv[a] = gatev[a*16 + l15];
        #pragma unroll
        for (int dtile = 0; dtile < 4; ++dtile) {
            float sr[4];
            #pragma unroll
            for (int r = 0; r < 4; ++r) {
                float s = cacc[dtile][0][r]*gv[0] + cacc[dtile][1][r]*gv[1]
                        + cacc[dtile][2][r]*gv[2] + cacc[dtile][3][r]*gv[3];
                s += __shfl_xor(s, 1); s += __shfl_xor(s, 2);
                s += __shfl_xor(s, 4); s += __shfl_xor(s, 8);
                sr[r] = s;
            }
            if (l15 == 0) {
                uint2 pk; pk.x = pack2(sr[0], sr[1]); pk.y = pack2(sr[2], sr[3]);
                *(uint2*)(wctx_ws + (size_t)g*512 + h*64 + dtile*16 + quad*4) = pk;
            }
        }
    }
}

__global__ __launch_bounds__(256, 4)
void outproj_kernel(const unsigned short* __restrict__ wo_bf,
                    const unsigned short* __restrict__ wctx_bf,
                    const float* __restrict__ bo,
                    const float* __restrict__ sumgate,
                    float* __restrict__ out)
{
    const int tid  = threadIdx.x;
    const int w    = tid >> 6;
    const int lane = tid & 63;
    const int l15  = lane & 15;
    const int quad = lane >> 4;
    const int g0   = blockIdx.x * 16;
    const int e0   = blockIdx.y * 64;

    f32x4 oac = (f32x4){0.f,0.f,0.f,0.f};
    #pragma unroll 4
    for (int ks = 0; ks < 16; ++ks) {
        const int col = ks*32 + quad*8;
        short8 a = *(const short8*)(wctx_bf + (size_t)(g0 + l15)*D_ + col);
        short8 b = *(const short8*)(wo_bf + (size_t)(e0 + w*16 + l15)*D_ + col);
        oac = __builtin_amdgcn_mfma_f32_16x16x32_bf16(a, b, oac, 0,0,0);
    }
    const int e = e0 + w*16 + l15;
    const float bov = bo[e];
    #pragma unroll
    for (int r = 0; r < 4; ++r) {
        const int gg = g0 + quad*4 + r;
        out[(size_t)gg*D_ + e] = oac[r] + sumgate[gg] * bov;
    }
}

extern "C" void kernel_launch(void* const* d_in, const int* in_sizes, int n_in,
                              void* d_out, int out_size, void* d_ws, size_t ws_size,
                              hipStream_t stream) {
    const float* x    = (const float*)d_in[0];
    // d_in[1] = batch (int64) — unused: graphs are equal-sized (64 nodes)
    const float* wqkv = (const float*)d_in[2];
    const float* bqkv = (const float*)d_in[3];
    const float* wo   = (const float*)d_in[4];
    const float* bo   = (const float*)d_in[5];
    const float* gw   = (const float*)d_in[6];
    const float* gb   = (const float*)d_in[7];
    float* out = (float*)d_out;

    char* ws = (char*)d_ws;
    unsigned short* wbf     = (unsigned short*)(ws + WQKV_OFF);
    unsigned short* wo_bf   = (unsigned short*)(ws + WO_OFF);
    float*          upart   = (float*)(ws + UPART_OFF);
    float*          sg_ws   = (float*)(ws + SG_OFF);
    unsigned short* wctx_ws = (unsigned short*)(ws + WCTX_OFF);

    const int total = in_sizes[0] / D_;  // 65536 nodes
    int G = total / 64;                  // 1024 graphs

    // ---- try the single cooperative kernel ----
    void* args[] = { (void*)&x, (void*)&wqkv, (void*)&wo, (void*)&bqkv,
                     (void*)&bo, (void*)&gw, (void*)&gb, (void*)&wbf,
                     (void*)&upart, (void*)&wctx_ws, (void*)&sg_ws,
                     (void*)&out, (void*)&G };
    hipError_t err = hipLaunchCooperativeKernel((const void*)fused_all,
                                                dim3(256), dim3(512),
                                                args, 0, stream);
    if (err == hipSuccess) return;
    (void)hipGetLastError();   // clear sticky error, fall back

    // ---- fallback: v10's proven 3-kernel path ----
    hipLaunchKernelGGL(convert_weights, dim3(1040), dim3(256), 0, stream,
                       wqkv, wo, wbf, gw, upart);
    hipLaunchKernelGGL(attn_ctx_kernel, dim3(G), dim3(512), 0, stream,
                       x, wbf, bqkv, upart, bo, gw, gb, wctx_ws, sg_ws);
    hipLaunchKernelGGL(outproj_kernel, dim3(G/16, 8), dim3(256), 0, stream,
                       wo_bf, wctx_ws, bo, sg_ws, out);
}

// Round 8
// 420.046 us; speedup vs baseline: 1.3905x; 1.3905x over previous
//
#include <hip/hip_runtime.h>
#include <stdint.h>

// AttentionReadout: G=1024 x N=64, D=512, H=8, hd=64. fp32 I/O, bf16 MFMA.
// v13 = v10 (proven 423.5us) with ONE change: QKV ks-loop unroll 4 -> 8.
// Mechanism: at (512,2) the reg cap is ~256 and v10 uses only ~172 total
// (108 arch, occupancy 2 waves/SIMD structural) -> ~80 spare regs. Unroll 8
// hoists 24 weight loads per group (vs 12), halving L2-latency exposures
// per dt from 4 to 2 with 2x the MFMA span to hide each. No occupancy
// change possible or intended.
// v12 post-mortem: single cooperative kernel total 584 (spill 124MB) BUT
// overhead = 584-464 = 120us with ONE launch == v10's 120us with three
// -> the ~120us is fixed harness overhead; fusion can never pay. Reverted.

typedef __attribute__((ext_vector_type(8))) short short8;   // 8 bf16
typedef __attribute__((ext_vector_type(4))) float f32x4;    // MFMA C/D frag

#define D_ 512

// ---- ws layout (bytes) ----
#define WQKV_OFF   0u          // 1536*512 bf16 = 1572864
#define WO_OFF     1572864u    // 512*512 bf16  = 524288
#define UPART_OFF  2097152u    // 16*512 f32    = 32768
#define SG_OFF     2132032u    // 1024 f32      = 4096
#define WCTX_OFF   2136128u    // 1024*512 bf16 = 1 MB

__device__ __forceinline__ unsigned short f2bf(float f) {
    union { float f; unsigned int u; } t; t.f = f;
    unsigned int u = t.u;
    return (unsigned short)((u + 0x7FFFu + ((u >> 16) & 1u)) >> 16);  // RNE
}
__device__ __forceinline__ unsigned pack2(float a, float b) {
    return (unsigned)f2bf(a) | ((unsigned)f2bf(b) << 16);
}

// ---- pre-pass: wqkv + wo fp32 -> bf16; blocks >=1024 compute u partials ----
__global__ __launch_bounds__(256)
void convert_weights(const float* __restrict__ wqkv, const float* __restrict__ wo,
                     unsigned short* __restrict__ wbf,
                     const float* __restrict__ gw, float* __restrict__ upart) {
    if (blockIdx.x >= 1024) {   // upart[b][d] = sum_{e in b*32..+32} wo[e][d]*gw[e]
        const int b = blockIdx.x - 1024;
        const int t = threadIdx.x;
        float a0 = 0.f, a1 = 0.f;
        #pragma unroll 4
        for (int e = b * 32; e < b * 32 + 32; ++e) {
            const float ge = gw[e];
            a0 += wo[(size_t)e * 512 + t]       * ge;
            a1 += wo[(size_t)e * 512 + t + 256] * ge;
        }
        upart[b * 512 + t] = a0; upart[b * 512 + t + 256] = a1;
        return;
    }
    const int i4 = blockIdx.x * 256 + threadIdx.x;          // 262144 float4 total
    float4 v;
    if (i4 < 196608) v = *(const float4*)(wqkv + (size_t)i4 * 4);
    else             v = *(const float4*)(wo   + (size_t)(i4 - 196608) * 4);
    uint2 p; p.x = pack2(v.x, v.y); p.y = pack2(v.z, v.w);
    *(uint2*)(wbf + (size_t)i4 * 4) = p;
}

union U8 { unsigned u[4]; short8 s; };

// ---- main: per-graph, wave-per-head, barrier-free middle ----
__global__ __launch_bounds__(512, 2)
void attn_ctx_kernel(const float* __restrict__ x,             // [65536,512] f32
                     const unsigned short* __restrict__ wqkv, // [1536,512] bf16
                     const float* __restrict__ bqkv,          // [1536] f32
                     const float* __restrict__ upart,         // [16,512] f32
                     const float* __restrict__ bo,            // [512] f32
                     const float* __restrict__ gw,            // [512] f32
                     const float* __restrict__ gb,            // [1] f32
                     unsigned short* __restrict__ wctx_ws,    // [1024,512] bf16
                     float* __restrict__ sumgate)             // [1024] f32
{
    __shared__ unsigned short xs[64][520];     // 66560 B  x slab (bf16)
    __shared__ unsigned short scr[8][64][72];  // 73728 B  per-wave scratch (vT then P)
    __shared__ float logitp[8][64];            // 2048 B
    __shared__ float gatev[64];                // 256 B
    __shared__ float u_s[512];                 // 2048 B
    __shared__ float c0_s;
    // total ~144.7 KB -> 1 block/CU, 8 waves (2/SIMD)

    const int g    = blockIdx.x;
    const int tid  = threadIdx.x;
    const int w    = tid >> 6;      // wave = head
    const int lane = tid & 63;
    const int l15  = lane & 15;
    const int quad = lane >> 4;

    // ---- stage x once: fp32 -> bf16 LDS; u = sum(upart); c0 = bo.gw+gb ----
    #pragma unroll
    for (int i = 0; i < 16; ++i) {
        int idx = tid + i * 512;
        int row = idx >> 7;
        int c4  = idx & 127;
        float4 v = *(const float4*)(x + ((size_t)(g*64 + row))*512 + c4*4);
        uint2 p; p.x = pack2(v.x, v.y); p.y = pack2(v.z, v.w);
        *(uint2*)(&xs[row][c4*4]) = p;
    }
    {
        float s = 0.f;
        #pragma unroll
        for (int b = 0; b < 16; ++b) s += upart[b*512 + tid];
        u_s[tid] = s;
    }
    if (tid < 64) {                 // wave 0: c0 = bo.gw + gb (full-wave reduce)
        float s = 0.f;
        #pragma unroll
        for (int i = 0; i < 8; ++i) s += bo[tid*8 + i] * gw[tid*8 + i];
        s += __shfl_xor(s, 1);  s += __shfl_xor(s, 2);  s += __shfl_xor(s, 4);
        s += __shfl_xor(s, 8);  s += __shfl_xor(s, 16); s += __shfl_xor(s, 32);
        if (tid == 0) c0_s = s + gb[0];
    }
    __syncthreads();

    const int h = w;
    unsigned short (*S)[72] = scr[w];

    // ======== QKV for head h (K=512), building score frags in-register ========
    U8 qA[4][2], kB[4][2];   // [n-strip][ks2] A/B frags for scores
    #pragma unroll
    for (int dt = 0; dt < 4; ++dt) {
        f32x4 aq[4], ak[4], av[4];
        #pragma unroll
        for (int nt = 0; nt < 4; ++nt) {
            aq[nt] = (f32x4){0.f,0.f,0.f,0.f};
            ak[nt] = (f32x4){0.f,0.f,0.f,0.f};
            av[nt] = (f32x4){0.f,0.f,0.f,0.f};
        }
        const unsigned short* wq = wqkv + (size_t)(          h*64 + dt*16 + l15) * 512;
        const unsigned short* wk = wqkv + (size_t)( 512 +    h*64 + dt*16 + l15) * 512;
        const unsigned short* wv = wqkv + (size_t)(1024 +    h*64 + dt*16 + l15) * 512;
        #pragma unroll 8
        for (int ks = 0; ks < 16; ++ks) {   // v13: unroll 4 -> 8 (2x load-ahead)
            const int col = ks*32 + quad*8;
            short8 a0 = *(const short8*)(wq + col);
            short8 a1 = *(const short8*)(wk + col);
            short8 a2 = *(const short8*)(wv + col);
            #pragma unroll
            for (int nt = 0; nt < 4; ++nt) {
                short8 b = *(const short8*)(&xs[nt*16 + l15][col]);
                aq[nt] = __builtin_amdgcn_mfma_f32_16x16x32_bf16(a0, b, aq[nt], 0,0,0);
                ak[nt] = __builtin_amdgcn_mfma_f32_16x16x32_bf16(a1, b, ak[nt], 0,0,0);
                av[nt] = __builtin_amdgcn_mfma_f32_16x16x32_bf16(a2, b, av[nt], 0,0,0);
            }
        }
        // biases for this lane's d = dt*16 + quad*4 + r
        float bq[4], bk2[4], bv2[4];
        #pragma unroll
        for (int r = 0; r < 4; ++r) {
            bq[r]  = bqkv[          h*64 + dt*16 + quad*4 + r];
            bk2[r] = bqkv[ 512 +    h*64 + dt*16 + quad*4 + r];
            bv2[r] = bqkv[1024 +    h*64 + dt*16 + quad*4 + r];
        }
        const bool take = ((quad >> 1) == (dt & 1));
        const int  ks2  = dt >> 1;
        #pragma unroll
        for (int nt = 0; nt < 4; ++nt) {
            // q/k C-layout [d][n] -> frag [n][d] via quad shuffles
            unsigned q01 = pack2(aq[nt][0]+bq[0],  aq[nt][1]+bq[1]);
            unsigned q23 = pack2(aq[nt][2]+bq[2],  aq[nt][3]+bq[3]);
            unsigned k01 = pack2(ak[nt][0]+bk2[0], ak[nt][1]+bk2[1]);
            unsigned k23 = pack2(ak[nt][2]+bk2[2], ak[nt][3]+bk2[3]);
            #pragma unroll
            for (int j = 0; j < 4; ++j) {
                int srcl = ((quad & 1)*2 + (j >> 1))*16 + l15;
                unsigned tq = (unsigned)__shfl((int)((j & 1) ? q23 : q01), srcl);
                unsigned tk = (unsigned)__shfl((int)((j & 1) ? k23 : k01), srcl);
                if (take) { qA[nt][ks2].u[j] = tq; kB[nt][ks2].u[j] = tk; }
            }
            // v (+bias) -> scratch as vT[d][m]
            #pragma unroll
            for (int r = 0; r < 4; ++r)
                S[dt*16 + quad*4 + r][nt*16 + l15] = f2bf(av[nt][r] + bv2[r]);
        }
    }

    // ======== scores S[n][m] = q.k^T / 8 (full 64x64 per wave) ========
    f32x4 sacc[4][4];
    #pragma unroll
    for (int a = 0; a < 4; ++a)
        #pragma unroll
        for (int b = 0; b < 4; ++b) sacc[a][b] = (f32x4){0.f,0.f,0.f,0.f};
    #pragma unroll
    for (int ks2 = 0; ks2 < 2; ++ks2)
        #pragma unroll
        for (int a = 0; a < 4; ++a)
            #pragma unroll
            for (int b = 0; b < 4; ++b)
                sacc[a][b] = __builtin_amdgcn_mfma_f32_16x16x32_bf16(
                                 qA[a][ks2].s, kB[b][ks2].s, sacc[a][b], 0,0,0);

    // ======== softmax over m (per row n = a*16 + quad*4 + r) ========
    #pragma unroll
    for (int a = 0; a < 4; ++a) {
        #pragma unroll
        for (int r = 0; r < 4; ++r) {
            float m0 = -1e30f;
            #pragma unroll
            for (int b = 0; b < 4; ++b) { sacc[a][b][r] *= 0.125f; m0 = fmaxf(m0, sacc[a][b][r]); }
            m0 = fmaxf(m0, __shfl_xor(m0, 1));
            m0 = fmaxf(m0, __shfl_xor(m0, 2));
            m0 = fmaxf(m0, __shfl_xor(m0, 4));
            m0 = fmaxf(m0, __shfl_xor(m0, 8));
            float s = 0.f;
            #pragma unroll
            for (int b = 0; b < 4; ++b) { float e = __expf(sacc[a][b][r] - m0); sacc[a][b][r] = e; s += e; }
            s += __shfl_xor(s, 1); s += __shfl_xor(s, 2); s += __shfl_xor(s, 4); s += __shfl_xor(s, 8);
            float inv = 1.0f / s;
            #pragma unroll
            for (int b = 0; b < 4; ++b) sacc[a][b][r] *= inv;
        }
    }

    // ======== extract vA frags BEFORE overwriting scratch with P ========
    U8 vA[4][2];
    #pragma unroll
    for (int dtile = 0; dtile < 4; ++dtile)
        #pragma unroll
        for (int ks2 = 0; ks2 < 2; ++ks2)
            vA[dtile][ks2].s = *(const short8*)(&S[dtile*16 + l15][ks2*32 + quad*8]);

    // ======== P -> scratch [n][m] (in-order DS after vA reads) ========
    #pragma unroll
    for (int a = 0; a < 4; ++a)
        #pragma unroll
        for (int b = 0; b < 4; ++b)
            #pragma unroll
            for (int r = 0; r < 4; ++r)
                S[a*16 + quad*4 + r][b*16 + l15] = f2bf(sacc[a][b][r]);

    U8 pB[4][2];
    #pragma unroll
    for (int a = 0; a < 4; ++a)
        #pragma unroll
        for (int ks2 = 0; ks2 < 2; ++ks2)
            pB[a][ks2].s = *(const short8*)(&S[a*16 + l15][ks2*32 + quad*8]);

    // ======== PV: ctxT[d][n] = vT @ P^T ========
    f32x4 cacc[4][4];   // [dtile][a]; lane: d = dtile*16+quad*4+r, n = a*16+l15
    #pragma unroll
    for (int dtile = 0; dtile < 4; ++dtile)
        #pragma unroll
        for (int a = 0; a < 4; ++a) cacc[dtile][a] = (f32x4){0.f,0.f,0.f,0.f};
    #pragma unroll
    for (int ks2 = 0; ks2 < 2; ++ks2)
        #pragma unroll
        for (int dtile = 0; dtile < 4; ++dtile)
            #pragma unroll
            for (int a = 0; a < 4; ++a)
                cacc[dtile][a] = __builtin_amdgcn_mfma_f32_16x16x32_bf16(
                                     vA[dtile][ks2].s, pB[a][ks2].s, cacc[dtile][a], 0,0,0);

    // ======== gate-logit partials: logit[n] += sum_d ctx[n][d] u[h*64+d] ========
    {
        float uv[4][4];
        #pragma unroll
        for (int dtile = 0; dtile < 4; ++dtile)
            #pragma unroll
            for (int r = 0; r < 4; ++r)
                uv[dtile][r] = u_s[h*64 + dtile*16 + quad*4 + r];
        #pragma unroll
        for (int a = 0; a < 4; ++a) {
            float s = 0.f;
            #pragma unroll
            for (int dtile = 0; dtile < 4; ++dtile)
                #pragma unroll
                for (int r = 0; r < 4; ++r)
                    s += cacc[dtile][a][r] * uv[dtile][r];
            s += __shfl_xor(s, 16); s += __shfl_xor(s, 32);   // sum over quads
            if (quad == 0) logitp[w][a*16 + l15] = s;
        }
    }
    __syncthreads();   // logitp complete (all waves)

    if (tid < 64) {
        float lg = c0_s;
        #pragma unroll
        for (int ww = 0; ww < 8; ++ww) lg += logitp[ww][tid];
        float gt = 1.0f / (1.0f + __expf(-lg));
        gatev[tid] = gt;
        float s = gt;
        s += __shfl_xor(s, 1);  s += __shfl_xor(s, 2);  s += __shfl_xor(s, 4);
        s += __shfl_xor(s, 8);  s += __shfl_xor(s, 16); s += __shfl_xor(s, 32);
        if (tid == 0) sumgate[g] = s;
    }
    __syncthreads();

    // ======== wctx[d] = sum_n gate[n] ctx[n][d] (wave-exclusive d range) ========
    {
        float gv[4];
        #pragma unroll
        for (int a = 0; a < 4; ++a) gv[a] = gatev[a*16 + l15];
        #pragma unroll
        for (int dtile = 0; dtile < 4; ++dtile) {
            float sr[4];
            #pragma unroll
            for (int r = 0; r < 4; ++r) {
                float s = cacc[dtile][0][r]*gv[0] + cacc[dtile][1][r]*gv[1]
                        + cacc[dtile][2][r]*gv[2] + cacc[dtile][3][r]*gv[3];
                s += __shfl_xor(s, 1); s += __shfl_xor(s, 2);
                s += __shfl_xor(s, 4); s += __shfl_xor(s, 8);   // sum over l15
                sr[r] = s;
            }
            if (l15 == 0) {
                uint2 pk; pk.x = pack2(sr[0], sr[1]); pk.y = pack2(sr[2], sr[3]);
                *(uint2*)(wctx_ws + (size_t)g*512 + h*64 + dtile*16 + quad*4) = pk;
            }
        }
    }
}

// ---- out-projection: grid (G/16, 8); block = 16 g x 64 e, 4 waves ----
__global__ __launch_bounds__(256, 4)
void outproj_kernel(const unsigned short* __restrict__ wo_bf,   // [512,512] bf16
                    const unsigned short* __restrict__ wctx_bf, // [G,512] bf16
                    const float* __restrict__ bo,               // [512] f32
                    const float* __restrict__ sumgate,          // [G] f32
                    float* __restrict__ out)                    // [G,512] f32
{
    const int tid  = threadIdx.x;
    const int w    = tid >> 6;
    const int lane = tid & 63;
    const int l15  = lane & 15;
    const int quad = lane >> 4;
    const int g0   = blockIdx.x * 16;
    const int e0   = blockIdx.y * 64;

    f32x4 oac = (f32x4){0.f,0.f,0.f,0.f};
    #pragma unroll 4
    for (int ks = 0; ks < 16; ++ks) {
        const int col = ks*32 + quad*8;
        short8 a = *(const short8*)(wctx_bf + (size_t)(g0 + l15)*D_ + col);
        short8 b = *(const short8*)(wo_bf + (size_t)(e0 + w*16 + l15)*D_ + col);
        oac = __builtin_amdgcn_mfma_f32_16x16x32_bf16(a, b, oac, 0,0,0);
    }
    const int e = e0 + w*16 + l15;
    const float bov = bo[e];
    #pragma unroll
    for (int r = 0; r < 4; ++r) {
        const int gg = g0 + quad*4 + r;
        out[(size_t)gg*D_ + e] = oac[r] + sumgate[gg] * bov;
    }
}

extern "C" void kernel_launch(void* const* d_in, const int* in_sizes, int n_in,
                              void* d_out, int out_size, void* d_ws, size_t ws_size,
                              hipStream_t stream) {
    const float* x    = (const float*)d_in[0];
    // d_in[1] = batch (int64) — unused: graphs are equal-sized (64 nodes)
    const float* wqkv = (const float*)d_in[2];
    const float* bqkv = (const float*)d_in[3];
    const float* wo   = (const float*)d_in[4];
    const float* bo   = (const float*)d_in[5];
    const float* gw   = (const float*)d_in[6];
    const float* gb   = (const float*)d_in[7];
    float* out = (float*)d_out;

    char* ws = (char*)d_ws;
    unsigned short* wqkv_bf = (unsigned short*)(ws + WQKV_OFF);
    unsigned short* wo_bf   = (unsigned short*)(ws + WO_OFF);
    float*          upart   = (float*)(ws + UPART_OFF);
    float*          sg_ws   = (float*)(ws + SG_OFF);
    unsigned short* wctx_ws = (unsigned short*)(ws + WCTX_OFF);

    const int total = in_sizes[0] / D_;  // 65536 nodes
    const int G     = total / 64;        // 1024 graphs

    hipLaunchKernelGGL(convert_weights, dim3(1040), dim3(256), 0, stream,
                       wqkv, wo, wqkv_bf, gw, upart);
    hipLaunchKernelGGL(attn_ctx_kernel, dim3(G), dim3(512), 0, stream,
                       x, wqkv_bf, bqkv, upart, bo, gw, gb, wctx_ws, sg_ws);
    hipLaunchKernelGGL(outproj_kernel, dim3(G/16, 8), dim3(256), 0, stream,
                       wo_bf, wctx_ws, bo, sg_ws, out);
}